// Round 3
// baseline (94.834 us; speedup 1.0000x reference)
//
#include <hip/hip_runtime.h>

#define HH 1024
#define WW 1024
#define NRW 16                        // rows per wave-strip
#define STRIPS (HH / NRW)             // 64 strips per image
#define NWAVES (32 * STRIPS)          // 2048 waves
#define NBLK (NWAVES / 4)             // 512 blocks of 4 waves

__device__ __forceinline__ float4 ldq(const float* __restrict__ img, int y, int q, int lane) {
    return reinterpret_cast<const float4*>(img + (size_t)y * WW)[64 * q + lane];
}

__global__ __launch_bounds__(256, 2) void sobel_loss_kernel(
    const float* __restrict__ fake, const float* __restrict__ real,
    double* __restrict__ acc_num, unsigned long long* __restrict__ acc_cnt)
{
    const int lane  = threadIdx.x & 63;
    const int wv    = threadIdx.x >> 6;
    const int strip = blockIdx.x * 4 + wv;        // 0..2047
    const int img   = strip >> 6;                 // strip / 64
    const int y0    = (strip & 63) * NRW;

    const float* f = fake + (size_t)img * HH * WW;
    const float* r = real + (size_t)img * HH * WW;

    // rolling 3-row window: lane owns 16 px of the row as 4 chunk-strided float4
    float4 fprev[4], fcur[4], rprev[4], rcur[4];
    const int ym = max(y0 - 1, 0);
    #pragma unroll
    for (int q = 0; q < 4; ++q) {
        fprev[q] = ldq(f, ym, q, lane);
        rprev[q] = ldq(r, ym, q, lane);
        fcur[q]  = ldq(f, y0, q, lane);
        rcur[q]  = ldq(r, y0, q, lane);
    }

    float num = 0.f;
    int   cnt = 0;

    #pragma unroll
    for (int i = 0; i < NRW; ++i) {
        const int yn = min(y0 + i + 1, HH - 1);
        float4 fnext[4], rnext[4];
        #pragma unroll
        for (int q = 0; q < 4; ++q) {
            fnext[q] = ldq(f, yn, q, lane);
            rnext[q] = ldq(r, yn, q, lane);
        }

        // vertical smooth S = (p + 2c) + n  — exact jax FP order
        float4 Sf[4], Sr[4];
        #pragma unroll
        for (int q = 0; q < 4; ++q) {
            Sf[q].x = fprev[q].x + 2.f * fcur[q].x + fnext[q].x;
            Sf[q].y = fprev[q].y + 2.f * fcur[q].y + fnext[q].y;
            Sf[q].z = fprev[q].z + 2.f * fcur[q].z + fnext[q].z;
            Sf[q].w = fprev[q].w + 2.f * fcur[q].w + fnext[q].w;
            Sr[q].x = rprev[q].x + 2.f * rcur[q].x + rnext[q].x;
            Sr[q].y = rprev[q].y + 2.f * rcur[q].y + rnext[q].y;
            Sr[q].z = rprev[q].z + 2.f * rcur[q].z + rnext[q].z;
            Sr[q].w = rprev[q].w + 2.f * rcur[q].w + rnext[q].w;
        }

        // horizontal neighbors: all intra-wave shuffles (chunk q covers px [256q, 256q+256))
        #pragma unroll
        for (int q = 0; q < 4; ++q) {
            // S[x0-1]: lane i>0 <- lane i-1's S[q].w ; lane 0 <- lane 63's S[q-1].w (or clamp at q==0)
            const float fup = __shfl_up(Sf[q].w, 1);
            const float rup = __shfl_up(Sr[q].w, 1);
            const float fcc = (q == 0) ? Sf[0].x : __shfl(Sf[q - 1].w, 63);
            const float rcc = (q == 0) ? Sr[0].x : __shfl(Sr[q - 1].w, 63);
            const float Sfm = (lane == 0) ? fcc : fup;
            const float Srm = (lane == 0) ? rcc : rup;
            // S[x0+4]: lane i<63 <- lane i+1's S[q].x ; lane 63 <- lane 0's S[q+1].x (or clamp at q==3)
            const float fdn = __shfl_down(Sf[q].x, 1);
            const float rdn = __shfl_down(Sr[q].x, 1);
            const float fnc = (q == 3) ? Sf[3].w : __shfl(Sf[q + 1].x, 0);
            const float rnc = (q == 3) ? Sr[3].w : __shfl(Sr[q + 1].x, 0);
            const float Sfp = (lane == 63) ? fnc : fdn;
            const float Srp = (lane == 63) ? rnc : rdn;

            float ef, er;
            er = Sr[q].y - Srm;     ef = Sf[q].y - Sfm;     if (er > 0.f) { num += fabsf(ef - er); ++cnt; }
            er = Sr[q].z - Sr[q].x; ef = Sf[q].z - Sf[q].x; if (er > 0.f) { num += fabsf(ef - er); ++cnt; }
            er = Sr[q].w - Sr[q].y; ef = Sf[q].w - Sf[q].y; if (er > 0.f) { num += fabsf(ef - er); ++cnt; }
            er = Srp - Sr[q].z;     ef = Sfp - Sf[q].z;     if (er > 0.f) { num += fabsf(ef - er); ++cnt; }
        }

        #pragma unroll
        for (int q = 0; q < 4; ++q) {
            fprev[q] = fcur[q]; fcur[q] = fnext[q];
            rprev[q] = rcur[q]; rcur[q] = rnext[q];
        }
    }

    // wave64 reduce; one atomic pair per wave (no LDS, no barrier)
    for (int off = 32; off; off >>= 1) {
        num += __shfl_down(num, off);
        cnt += __shfl_down(cnt, off);
    }
    if (lane == 0) {
        atomicAdd(acc_num, (double)num);
        atomicAdd(acc_cnt, (unsigned long long)cnt);
    }
}

__global__ void finalize_kernel(const double* __restrict__ acc_num,
                                const unsigned long long* __restrict__ acc_cnt,
                                float* __restrict__ out)
{
    const double c = (double)(*acc_cnt);
    out[0] = (float)((*acc_num) / c / 32.0);
}

extern "C" void kernel_launch(void* const* d_in, const int* in_sizes, int n_in,
                              void* d_out, int out_size, void* d_ws, size_t ws_size,
                              hipStream_t stream)
{
    const float* fake = (const float*)d_in[0];
    const float* real = (const float*)d_in[1];
    float* out = (float*)d_out;

    double* acc_num             = (double*)d_ws;
    unsigned long long* acc_cnt = (unsigned long long*)((char*)d_ws + 8);

    hipMemsetAsync(d_ws, 0, 16, stream);
    sobel_loss_kernel<<<NBLK, 256, 0, stream>>>(fake, real, acc_num, acc_cnt);
    finalize_kernel<<<1, 1, 0, stream>>>(acc_num, acc_cnt, out);
}